// Round 23
// baseline (140.959 us; speedup 1.0000x reference)
//
#include <hip/hip_runtime.h>
#include <hip/hip_bf16.h>
#include <math.h>

#define N_NODES 100000
#define N_EDGES 1600000
#define IN_F 256
#define HID 32
#define OUTC 16
#define NBUCK 1000
#define BUCK_W 100     // NBUCK * BUCK_W == N_NODES
#define NBB 256        // partition blocks
#define CHUNK 6250     // N_EDGES / NBB
#define MAXE 4096      // per-chunk edge capacity in LDS
#define K1_BLOCKS ((N_NODES + 63) / 64)   // 1563

typedef unsigned short ushort_t;
typedef unsigned int uint_t;
typedef __attribute__((ext_vector_type(8))) short bf16x8;
typedef __attribute__((ext_vector_type(4))) float f32x4;

__device__ inline ushort_t f2bf(float f) {
    union { float f; uint_t u; } v; v.f = f;
    uint_t r = v.u + 0x7fff + ((v.u >> 16) & 1);
    return (ushort_t)(r >> 16);
}
__device__ inline float bf2f(ushort_t h) {
    union { uint_t u; float f; } v; v.u = (uint_t)h << 16;
    return v.f;
}
__device__ inline float bf_lo(uint_t d) {
    union { uint_t u; float f; } v; v.u = d << 16;
    return v.f;
}
__device__ inline float bf_hi(uint_t d) {
    union { uint_t u; float f; } v; v.u = d & 0xFFFF0000u;
    return v.f;
}
__device__ inline bf16x8 packA(const float4& lo, const float4& hi) {
    bf16x8 a;
    a[0] = (short)f2bf(lo.x); a[1] = (short)f2bf(lo.y);
    a[2] = (short)f2bf(lo.z); a[3] = (short)f2bf(lo.w);
    a[4] = (short)f2bf(hi.x); a[5] = (short)f2bf(hi.y);
    a[6] = (short)f2bf(hi.z); a[7] = (short)f2bf(hi.w);
    return a;
}
__device__ inline void gload_lds16(const void* g, void* l) {
    __builtin_amdgcn_global_load_lds((const __attribute__((address_space(1))) void*)g,
                                     (__attribute__((address_space(3))) void*)l, 16, 0, 0);
}

// ============ MERGED: blocks 0..NBB-1 = bucket histogram; block NBB = weight fusion ============
__global__ __launch_bounds__(256) void k_cnt_wfuse(
    const int* __restrict__ ei, int* __restrict__ bhist,
    const float* __restrict__ w1a_w, const float* __restrict__ w1a_b,
    const float* __restrict__ w1b_w, const float* __restrict__ w1b_b,
    ushort_t* __restrict__ wpack, float* __restrict__ bp)
{
    __shared__ char smem[32 * 1024 + 4 * 1024 + 256];
    const int t = threadIdx.x;

    if (blockIdx.x < NBB) {
        int* lh = (int*)smem;
        const int blk = blockIdx.x;
        for (int b = t; b < NBUCK; b += 256) lh[b] = 0;
        __syncthreads();
        const int base = blk * CHUNK;
        for (int i = t; i < CHUNK; i += 256) {
            const int dst = ei[N_EDGES + base + i];
            atomicAdd(&lh[dst / BUCK_W], 1);
        }
        __syncthreads();
        for (int b = t; b < NBUCK; b += 256) bhist[b * NBB + blk] = lh[b];
        return;
    }

    float (*wps)[256] = (float (*)[256])smem;
    float (*wb_s)[32] = (float (*)[32])(smem + 32 * 1024);
    float* ba_s       = (float*)(smem + 36 * 1024);
    for (int i = t; i < 1024; i += 256) wb_s[i >> 5][i & 31] = w1b_w[i];
    if (t < 32) ba_s[t] = w1a_b[t];
    __syncthreads();
    const int k = t;
    for (int o = 0; o < 32; ++o) {
        float s = 0.f;
        #pragma unroll 8
        for (int c = 0; c < 32; ++c) s += wb_s[o][c] * w1a_w[c * 256 + k];
        wps[o][k] = s;
    }
    if (t < 32) {
        float s = 0.f;
        for (int c = 0; c < 32; ++c) s += wb_s[t][c] * ba_s[c];
        bp[t] = s + w1b_b[t];
    }
    __syncthreads();
    for (int idx = t; idx < 4 * 8 * 64 * 8; idx += 256) {
        const int j  = idx & 7;
        const int l  = (idx >> 3) & 63;
        const int ks = (idx >> 9) & 7;
        const int q  = idx >> 12;
        const int ncol = ((q & 1) << 4) + (l & 15);
        const int krow = ks * 32 + ((l >> 4) << 3) + j;
        const float v = (q < 2) ? w1a_w[ncol * 256 + krow] : wps[ncol][krow];
        wpack[idx] = f2bf(v);
    }
}

// ============ Pass 2a ============
__global__ __launch_bounds__(256) void k_scanH(const int* __restrict__ bhist,
                                               int* __restrict__ boffB, int* __restrict__ btot)
{
    __shared__ int sh[256];
    const int t = threadIdx.x;
    const int b = blockIdx.x;
    const int v = bhist[b * NBB + t];
    sh[t] = v;
    __syncthreads();
    #pragma unroll
    for (int off = 1; off < 256; off <<= 1) {
        const int u = (t >= off) ? sh[t - off] : 0;
        __syncthreads();
        sh[t] += u;
        __syncthreads();
    }
    boffB[b * NBB + t] = sh[t] - v;
    if (t == 255) btot[b] = sh[255];
}

// ============ Pass 2b ============
__global__ __launch_bounds__(1024) void k_scanH2(const int* __restrict__ btot,
                                                 int* __restrict__ bstart)
{
    __shared__ int sh[1024];
    const int t = threadIdx.x;
    const int v = (t < NBUCK) ? btot[t] : 0;
    sh[t] = v;
    __syncthreads();
    #pragma unroll
    for (int off = 1; off < 1024; off <<= 1) {
        const int u = (t >= off) ? sh[t - off] : 0;
        __syncthreads();
        sh[t] += u;
        __syncthreads();
    }
    if (t < NBUCK) bstart[t] = sh[t] - v;
    if (t == NBUCK - 1) bstart[NBUCK] = sh[t];
}

// ============ MERGED: blocks 0..NBB-1 = edge scatter; blocks NBB.. = layer-1 MFMA ============
// k1: x-tile (64 KB) staged via global_load_lds (async DMA, XOR-swizzled source);
// B-fragments read from global (L2-broadcast). 2 blocks/CU.
__global__ __launch_bounds__(256) void k_scat_k1(
    const int* __restrict__ ei,
    const int* __restrict__ boffB, const int* __restrict__ bstart,
    int* __restrict__ pairsP,
    const float* __restrict__ x,
    const float* __restrict__ w1a_b, const float* __restrict__ bp,
    const ushort_t* __restrict__ wpack,
    ushort_t* __restrict__ h1b, float* __restrict__ out1)
{
    __shared__ uint4 arena4[4096];      // 64 KB: scat uses 4KB as lcur; k1 uses as x tile
    const int t = threadIdx.x;

    if (blockIdx.x < NBB) {
        int* lcur = (int*)arena4;
        const int blk = blockIdx.x;
        for (int b = t; b < NBUCK; b += 256) lcur[b] = bstart[b] + boffB[b * NBB + blk];
        __syncthreads();
        const int base = blk * CHUNK;
        for (int i = t; i < CHUNK; i += 256) {
            const int src = ei[base + i];
            const int dst = ei[N_EDGES + base + i];
            const int b = dst / BUCK_W;
            const int pos = atomicAdd(&lcur[b], 1);
            pairsP[pos] = ((dst - b * BUCK_W) << 17) | src;
        }
        return;
    }

    char* arena = (char*)arena4;
    const int l64 = t & 63;
    const int wv  = t >> 6;
    const int node0 = (int)(blockIdx.x - NBB) * 64;

    // ---- stage x tile: node n row at LDS n*1024; pos p holds data-unit u = p ^ (n&7) ----
    #pragma unroll
    for (int i = 0; i < 16; ++i) {
        const int n = i * 4 + wv;                     // wave-uniform node in tile
        int gn = node0 + n;
        if (gn >= N_NODES) gn = N_NODES - 1;
        const char* gsrc = (const char*)x + (size_t)gn * 1024
                         + (size_t)((l64 ^ (n & 7)) * 16);
        char* ldst = arena + (size_t)n * 1024;        // wave-uniform base; HW adds lane*16
        gload_lds16(gsrc, ldst);
    }
    __syncthreads();

    const int arow = l64 & 15;
    const int kq   = l64 >> 4;
    const int nn   = wv * 16 + arow;                  // node row in tile
    const bf16x8* wf = (const bf16x8*)wpack;

    f32x4 accA0 = {0.f, 0.f, 0.f, 0.f};
    f32x4 accA1 = {0.f, 0.f, 0.f, 0.f};
    f32x4 accB0 = {0.f, 0.f, 0.f, 0.f};
    f32x4 accB1 = {0.f, 0.f, 0.f, 0.f};

    const char* xrow = arena + (size_t)nn * 1024;
    const int sw = nn & 7;

    #pragma unroll
    for (int ks = 0; ks < 8; ++ks) {
        const int u0 = ks * 8 + kq * 2;
        const float4 xlo = *(const float4*)(xrow + ((u0 ^ sw) * 16));
        const float4 xhi = *(const float4*)(xrow + (((u0 + 1) ^ sw) * 16));
        const bf16x8 a = packA(xlo, xhi);
        const bf16x8 bA0 = wf[(0 * 8 + ks) * 64 + l64];
        const bf16x8 bA1 = wf[(1 * 8 + ks) * 64 + l64];
        const bf16x8 bB0 = wf[(2 * 8 + ks) * 64 + l64];
        const bf16x8 bB1 = wf[(3 * 8 + ks) * 64 + l64];
        accA0 = __builtin_amdgcn_mfma_f32_16x16x32_bf16(a, bA0, accA0, 0, 0, 0);
        accA1 = __builtin_amdgcn_mfma_f32_16x16x32_bf16(a, bA1, accA1, 0, 0, 0);
        accB0 = __builtin_amdgcn_mfma_f32_16x16x32_bf16(a, bB0, accB0, 0, 0, 0);
        accB1 = __builtin_amdgcn_mfma_f32_16x16x32_bf16(a, bB1, accB1, 0, 0, 0);
    }

    const int ch = l64 & 15;
    const int rbase = (l64 >> 4) * 4;
    const float ba0 = w1a_b[ch];
    const float ba1 = w1a_b[ch + 16];
    const float bb0 = bp[ch];
    const float bb1 = bp[ch + 16];

    #pragma unroll
    for (int r = 0; r < 4; ++r) {
        const int node = node0 + wv * 16 + rbase + r;
        if (node < N_NODES) {
            h1b[(size_t)node * HID + ch]       = f2bf(accA0[r] + ba0);
            h1b[(size_t)node * HID + ch + 16]  = f2bf(accA1[r] + ba1);
            out1[(size_t)node * HID + ch]      = accB0[r] + bb0;
            out1[(size_t)node * HID + ch + 16] = accB1[r] + bb1;
        }
    }
}

// ============ Aggregate layer 1: 512 thr, uint gather (2 ch/lane), persist sort ============
__global__ __launch_bounds__(512) void k_agg32(const int* __restrict__ bstart,
                                               const int* __restrict__ pairsP,
                                               const ushort_t* __restrict__ h1b,
                                               float* __restrict__ out1,
                                               int* __restrict__ colg,
                                               int* __restrict__ offg)
{
    __shared__ int cnt[128];
    __shared__ int off[129];
    __shared__ int srt[MAXE];
    const int t = threadIdx.x;
    const int b = blockIdx.x;
    const int c2 = t & 15;
    const int grp = t >> 4;
    const uint_t* h1u = (const uint_t*)h1b;

    const int e0g = bstart[b];
    const int e1g = bstart[b + 1];
    const bool single = (e1g - e0g) <= MAXE;

    for (int ch0 = e0g; ch0 < e1g; ch0 += MAXE) {
        const int ce = (ch0 + MAXE < e1g) ? (ch0 + MAXE) : e1g;
        const int cn = ce - ch0;

        if (t < 128) cnt[t] = 0;
        __syncthreads();
        for (int i = t; i < cn; i += 512)
            atomicAdd(&cnt[pairsP[ch0 + i] >> 17], 1);
        __syncthreads();
        {
            int v = (t < 128) ? cnt[t] : 0;
            if (t < 128) off[t] = v;
            __syncthreads();
            #pragma unroll
            for (int o = 1; o < 128; o <<= 1) {
                int u = 0;
                if (t < 128 && t >= o) u = off[t - o];
                __syncthreads();
                if (t < 128) off[t] += u;
                __syncthreads();
            }
            if (t < 128) {
                const int inc = off[t];
                off[t] = inc - v;
                cnt[t] = inc - v;
                if (t == 127) off[128] = inc;
            }
        }
        __syncthreads();
        for (int i = t; i < cn; i += 512) {
            const int p = pairsP[ch0 + i];
            const int pos = atomicAdd(&cnt[p >> 17], 1);
            srt[pos] = p & 0x1FFFF;
        }
        __syncthreads();
        if (single) {
            for (int i = t; i < cn; i += 512) colg[ch0 + i] = srt[i];
            if (t <= BUCK_W) offg[b * (BUCK_W + 1) + t] = e0g + off[t];
        }
        for (int n = grp; n < BUCK_W; n += 32) {
            const int e0 = off[n];
            const int e1 = off[n + 1];
            float l0 = 0.f, h0 = 0.f, l1 = 0.f, h1 = 0.f;
            int e = e0;
            for (; e + 4 <= e1; e += 4) {
                const uint_t u0 = h1u[(size_t)srt[e]     * 16 + c2];
                const uint_t u1 = h1u[(size_t)srt[e + 1] * 16 + c2];
                const uint_t u2 = h1u[(size_t)srt[e + 2] * 16 + c2];
                const uint_t u3 = h1u[(size_t)srt[e + 3] * 16 + c2];
                l0 += bf_lo(u0); h0 += bf_hi(u0);
                l1 += bf_lo(u1); h1 += bf_hi(u1);
                l0 += bf_lo(u2); h0 += bf_hi(u2);
                l1 += bf_lo(u3); h1 += bf_hi(u3);
            }
            for (; e < e1; ++e) {
                const uint_t u = h1u[(size_t)srt[e] * 16 + c2];
                l0 += bf_lo(u); h0 += bf_hi(u);
            }
            float2* o = (float2*)&out1[((size_t)b * BUCK_W + n) * HID + 2 * c2];
            const float2 cur = *o;
            float2 nv;
            nv.x = fmaxf(cur.x + l0 + l1, 0.f);
            nv.y = fmaxf(cur.y + h0 + h1, 0.f);
            *o = nv;
        }
        __syncthreads();
    }
}

// ============ Layer 2 dense ============
__global__ __launch_bounds__(256) void k3_layer2_dense(
    const float* __restrict__ out1,
    const float* __restrict__ w2a_w, const float* __restrict__ w2a_b,
    const float* __restrict__ w2b_w, const float* __restrict__ w2b_b,
    ushort_t* __restrict__ h2b, float* __restrict__ out2)
{
    __shared__ float rs[64][33];
    __shared__ float h2s[64][17];
    __shared__ float wa[16][33];
    __shared__ float wb[16][17];

    const int t = threadIdx.x;
    const int node0 = blockIdx.x * 64;
    const int nrem = N_NODES - node0;

    for (int i = t; i < 16 * 32; i += 256)
        wa[i >> 5][i & 31] = w2a_w[i];
    if (t < 16 * 16) wb[t >> 4][t & 15] = w2b_w[t];
    for (int i = t; i < 64 * 32; i += 256) {
        int r = i >> 5, c = i & 31;
        float v = 0.f;
        if (r < nrem) v = out1[(size_t)(node0 + r) * HID + c];
        rs[r][c] = fmaxf(v, 0.f);
    }
    __syncthreads();

    const int o = t & 15;
    const int g = t >> 4;

    const float ba = w2a_b[o];
    float acc[4] = {};
    for (int c = 0; c < 32; ++c) {
        const float w = wa[o][c];
        #pragma unroll
        for (int j = 0; j < 4; ++j) acc[j] += rs[g * 4 + j][c] * w;
    }
    #pragma unroll
    for (int j = 0; j < 4; ++j) {
        const int ln = g * 4 + j;
        const float v = acc[j] + ba;
        h2s[ln][o] = v;
        if (ln < nrem) h2b[(size_t)(node0 + ln) * OUTC + o] = f2bf(v);
    }
    __syncthreads();

    const float bbv = w2b_b[o];
    float f[4] = {};
    for (int c = 0; c < 16; ++c) {
        const float w = wb[o][c];
        #pragma unroll
        for (int j = 0; j < 4; ++j) f[j] += h2s[g * 4 + j][c] * w;
    }
    #pragma unroll
    for (int j = 0; j < 4; ++j) {
        const int ln = g * 4 + j;
        if (ln < nrem) out2[(size_t)(node0 + ln) * OUTC + o] = f[j] + bbv;
    }
}

// ============ Aggregate layer 2 + log_softmax (uint gather, width-8 softmax) ============
__global__ __launch_bounds__(512) void k_agg16_sm(const int* __restrict__ bstart,
                                                  const int* __restrict__ pairsP,
                                                  const int* __restrict__ colg,
                                                  const int* __restrict__ offg,
                                                  const ushort_t* __restrict__ h2b,
                                                  float* __restrict__ out2)
{
    const int t = threadIdx.x;
    const int b = blockIdx.x;
    const int e0g = bstart[b];
    const int e1g = bstart[b + 1];
    const uint_t* h2u = (const uint_t*)h2b;

    if (e1g - e0g <= MAXE) {
        const int c2 = t & 7;
        const int grp = t >> 3;
        const int ob = b * (BUCK_W + 1);
        for (int n = grp; n < BUCK_W; n += 64) {
            const int e0 = offg[ob + n];
            const int e1 = offg[ob + n + 1];
            float l0 = 0.f, h0 = 0.f, l1 = 0.f, h1v = 0.f;
            int e = e0;
            for (; e + 4 <= e1; e += 4) {
                const uint_t u0 = h2u[(size_t)colg[e]     * 8 + c2];
                const uint_t u1 = h2u[(size_t)colg[e + 1] * 8 + c2];
                const uint_t u2 = h2u[(size_t)colg[e + 2] * 8 + c2];
                const uint_t u3 = h2u[(size_t)colg[e + 3] * 8 + c2];
                l0 += bf_lo(u0); h0 += bf_hi(u0);
                l1 += bf_lo(u1); h1v += bf_hi(u1);
                l0 += bf_lo(u2); h0 += bf_hi(u2);
                l1 += bf_lo(u3); h1v += bf_hi(u3);
            }
            for (; e < e1; ++e) {
                const uint_t u = h2u[(size_t)colg[e] * 8 + c2];
                l0 += bf_lo(u); h0 += bf_hi(u);
            }

            float2* op = (float2*)&out2[((size_t)b * BUCK_W + n) * OUTC + 2 * c2];
            const float2 cur = *op;
            const float v0 = cur.x + l0 + l1;
            const float v1 = cur.y + h0 + h1v;

            float m = fmaxf(v0, v1);
            #pragma unroll
            for (int o = 4; o > 0; o >>= 1)
                m = fmaxf(m, __shfl_xor(m, o, 8));
            float s = expf(v0 - m) + expf(v1 - m);
            #pragma unroll
            for (int o = 4; o > 0; o >>= 1)
                s += __shfl_xor(s, o, 8);
            const float lse = m + logf(s);
            float2 nv; nv.x = v0 - lse; nv.y = v1 - lse;
            *op = nv;
        }
        return;
    }

    __shared__ int cnt[128];
    __shared__ int off[129];
    __shared__ int srt[MAXE];
    const int c = t & 15;
    const int grp = t >> 4;

    for (int ch0 = e0g; ch0 < e1g; ch0 += MAXE) {
        const int ce = (ch0 + MAXE < e1g) ? (ch0 + MAXE) : e1g;
        const int cn = ce - ch0;
        const bool last = (ce == e1g);

        if (t < 128) cnt[t] = 0;
        __syncthreads();
        for (int i = t; i < cn; i += 512)
            atomicAdd(&cnt[pairsP[ch0 + i] >> 17], 1);
        __syncthreads();
        {
            int v = (t < 128) ? cnt[t] : 0;
            if (t < 128) off[t] = v;
            __syncthreads();
            #pragma unroll
            for (int o = 1; o < 128; o <<= 1) {
                int u = 0;
                if (t < 128 && t >= o) u = off[t - o];
                __syncthreads();
                if (t < 128) off[t] += u;
                __syncthreads();
            }
            if (t < 128) {
                const int inc = off[t];
                off[t] = inc - v;
                cnt[t] = inc - v;
                if (t == 127) off[128] = inc;
            }
        }
        __syncthreads();
        for (int i = t; i < cn; i += 512) {
            const int p = pairsP[ch0 + i];
            const int pos = atomicAdd(&cnt[p >> 17], 1);
            srt[pos] = p & 0x1FFFF;
        }
        __syncthreads();

        for (int n = grp; n < BUCK_W; n += 32) {
            const int e0 = off[n];
            const int e1 = off[n + 1];
            float acc = 0.f, acc2 = 0.f;
            int e = e0;
            for (; e + 1 < e1; e += 2) {
                acc += bf2f(h2b[(size_t)srt[e] * OUTC + c]);
                acc2 += bf2f(h2b[(size_t)srt[e + 1] * OUTC + c]);
            }
            if (e < e1) acc += bf2f(h2b[(size_t)srt[e] * OUTC + c]);
            acc += acc2;

            const size_t oidx = ((size_t)b * BUCK_W + n) * OUTC + c;
            if (!last) {
                out2[oidx] += acc;
            } else {
                const float val = out2[oidx] + acc;
                float m = val;
                #pragma unroll
                for (int o = 8; o > 0; o >>= 1)
                    m = fmaxf(m, __shfl_xor(m, o, 16));
                float s = expf(val - m);
                #pragma unroll
                for (int o = 8; o > 0; o >>= 1)
                    s += __shfl_xor(s, o, 16);
                const float lse = m + logf(s);
                out2[oidx] = val - lse;
            }
        }
        __syncthreads();
    }
}

extern "C" void kernel_launch(void* const* d_in, const int* in_sizes, int n_in,
                              void* d_out, int out_size, void* d_ws, size_t ws_size,
                              hipStream_t stream)
{
    const float* x      = (const float*)d_in[0];
    const float* w1a_w  = (const float*)d_in[1];
    const float* w1a_b  = (const float*)d_in[2];
    const float* w1b_w  = (const float*)d_in[3];
    const float* w1b_b  = (const float*)d_in[4];
    const float* w2a_w  = (const float*)d_in[5];
    const float* w2a_b  = (const float*)d_in[6];
    const float* w2b_w  = (const float*)d_in[7];
    const float* w2b_b  = (const float*)d_in[8];
    const int*   ei     = (const int*)d_in[9];
    float* out = (float*)d_out;

    // workspace (~38 MB)
    float*    out1   = (float*)d_ws;                              // 12.8 MB
    ushort_t* h1b    = (ushort_t*)(out1 + (size_t)N_NODES * HID); // 6.4 MB
    ushort_t* h2b    = h1b + (size_t)N_NODES * HID;               // 3.2 MB
    int*      pairsP = (int*)(h2b + (size_t)N_NODES * OUTC);      // 6.4 MB
    ushort_t* wpack  = (ushort_t*)(pairsP + N_EDGES);             // 32 KB
    float*    bp     = (float*)(wpack + 4 * 8 * 64 * 8);          // 32 f32
    int*      bhist  = (int*)(bp + 32);                           // 1 MB
    int*      boffB  = bhist + NBUCK * NBB;                       // 1 MB
    int*      btot   = boffB + NBUCK * NBB;                       // 1000
    int*      bstart = btot + NBUCK;                              // 1001
    int*      colg   = bstart + NBUCK + 1;                        // 6.4 MB
    int*      offg   = colg + N_EDGES;                            // ~404 KB

    k_cnt_wfuse<<<NBB + 1, 256, 0, stream>>>(ei, bhist,
                                             w1a_w, w1a_b, w1b_w, w1b_b, wpack, bp);
    k_scanH <<<NBUCK, 256, 0, stream>>>(bhist, boffB, btot);
    k_scanH2<<<1, 1024, 0, stream>>>(btot, bstart);
    k_scat_k1<<<NBB + K1_BLOCKS, 256, 0, stream>>>(ei, boffB, bstart, pairsP,
                                                   x, w1a_b, bp, wpack, h1b, out1);
    k_agg32<<<NBUCK, 512, 0, stream>>>(bstart, pairsP, h1b, out1, colg, offg);
    k3_layer2_dense<<<(N_NODES + 63) / 64, 256, 0, stream>>>(out1, w2a_w, w2a_b, w2b_w, w2b_b, h2b, out);
    k_agg16_sm<<<NBUCK, 512, 0, stream>>>(bstart, pairsP, colg, offg, h2b, out);
}

// Round 25
// 140.804 us; speedup vs baseline: 1.0011x; 1.0011x over previous
//
#include <hip/hip_runtime.h>
#include <hip/hip_bf16.h>
#include <math.h>

#define N_NODES 100000
#define N_EDGES 1600000
#define IN_F 256
#define HID 32
#define OUTC 16
#define NBUCK 1000
#define BUCK_W 100     // NBUCK * BUCK_W == N_NODES
#define NBB 256        // partition blocks
#define CHUNK 6250     // N_EDGES / NBB
#define MAXE 4096      // per-chunk edge capacity in LDS
#define NTILES 3125    // N_NODES / 32 (exact)
#define K1P 256        // persistent k1 blocks

typedef unsigned short ushort_t;
typedef unsigned int uint_t;
typedef __attribute__((ext_vector_type(8))) short bf16x8;
typedef __attribute__((ext_vector_type(4))) float f32x4;

__device__ inline ushort_t f2bf(float f) {
    union { float f; uint_t u; } v; v.f = f;
    uint_t r = v.u + 0x7fff + ((v.u >> 16) & 1);
    return (ushort_t)(r >> 16);
}
__device__ inline float bf2f(ushort_t h) {
    union { uint_t u; float f; } v; v.u = (uint_t)h << 16;
    return v.f;
}
__device__ inline float bf_lo(uint_t d) {
    union { uint_t u; float f; } v; v.u = d << 16;
    return v.f;
}
__device__ inline float bf_hi(uint_t d) {
    union { uint_t u; float f; } v; v.u = d & 0xFFFF0000u;
    return v.f;
}
__device__ inline bf16x8 packA(const float4& lo, const float4& hi) {
    bf16x8 a;
    a[0] = (short)f2bf(lo.x); a[1] = (short)f2bf(lo.y);
    a[2] = (short)f2bf(lo.z); a[3] = (short)f2bf(lo.w);
    a[4] = (short)f2bf(hi.x); a[5] = (short)f2bf(hi.y);
    a[6] = (short)f2bf(hi.z); a[7] = (short)f2bf(hi.w);
    return a;
}
__device__ inline void gload_lds16(const void* g, void* l) {
    __builtin_amdgcn_global_load_lds((const __attribute__((address_space(1))) void*)g,
                                     (__attribute__((address_space(3))) void*)l, 16, 0, 0);
}

// ============ MERGED: blocks 0..NBB-1 = bucket histogram; block NBB = weight fusion ============
__global__ __launch_bounds__(256) void k_cnt_wfuse(
    const int* __restrict__ ei, int* __restrict__ bhist,
    const float* __restrict__ w1a_w, const float* __restrict__ w1a_b,
    const float* __restrict__ w1b_w, const float* __restrict__ w1b_b,
    ushort_t* __restrict__ wpack, float* __restrict__ bp)
{
    __shared__ char smem[32 * 1024 + 4 * 1024 + 256];
    const int t = threadIdx.x;

    if (blockIdx.x < NBB) {
        int* lh = (int*)smem;
        const int blk = blockIdx.x;
        for (int b = t; b < NBUCK; b += 256) lh[b] = 0;
        __syncthreads();
        const int base = blk * CHUNK;
        for (int i = t; i < CHUNK; i += 256) {
            const int dst = ei[N_EDGES + base + i];
            atomicAdd(&lh[dst / BUCK_W], 1);
        }
        __syncthreads();
        for (int b = t; b < NBUCK; b += 256) bhist[b * NBB + blk] = lh[b];
        return;
    }

    float (*wps)[256] = (float (*)[256])smem;
    float (*wb_s)[32] = (float (*)[32])(smem + 32 * 1024);
    float* ba_s       = (float*)(smem + 36 * 1024);
    for (int i = t; i < 1024; i += 256) wb_s[i >> 5][i & 31] = w1b_w[i];
    if (t < 32) ba_s[t] = w1a_b[t];
    __syncthreads();
    const int k = t;
    for (int o = 0; o < 32; ++o) {
        float s = 0.f;
        #pragma unroll 8
        for (int c = 0; c < 32; ++c) s += wb_s[o][c] * w1a_w[c * 256 + k];
        wps[o][k] = s;
    }
    if (t < 32) {
        float s = 0.f;
        for (int c = 0; c < 32; ++c) s += wb_s[t][c] * ba_s[c];
        bp[t] = s + w1b_b[t];
    }
    __syncthreads();
    for (int idx = t; idx < 4 * 8 * 64 * 8; idx += 256) {
        const int j  = idx & 7;
        const int l  = (idx >> 3) & 63;
        const int ks = (idx >> 9) & 7;
        const int q  = idx >> 12;
        const int ncol = ((q & 1) << 4) + (l & 15);
        const int krow = ks * 32 + ((l >> 4) << 3) + j;
        const float v = (q < 2) ? w1a_w[ncol * 256 + krow] : wps[ncol][krow];
        wpack[idx] = f2bf(v);
    }
}

// ============ Pass 2a ============
__global__ __launch_bounds__(256) void k_scanH(const int* __restrict__ bhist,
                                               int* __restrict__ boffB, int* __restrict__ btot)
{
    __shared__ int sh[256];
    const int t = threadIdx.x;
    const int b = blockIdx.x;
    const int v = bhist[b * NBB + t];
    sh[t] = v;
    __syncthreads();
    #pragma unroll
    for (int off = 1; off < 256; off <<= 1) {
        const int u = (t >= off) ? sh[t - off] : 0;
        __syncthreads();
        sh[t] += u;
        __syncthreads();
    }
    boffB[b * NBB + t] = sh[t] - v;
    if (t == 255) btot[b] = sh[255];
}

// ============ Pass 2b ============
__global__ __launch_bounds__(1024) void k_scanH2(const int* __restrict__ btot,
                                                 int* __restrict__ bstart)
{
    __shared__ int sh[1024];
    const int t = threadIdx.x;
    const int v = (t < NBUCK) ? btot[t] : 0;
    sh[t] = v;
    __syncthreads();
    #pragma unroll
    for (int off = 1; off < 1024; off <<= 1) {
        const int u = (t >= off) ? sh[t - off] : 0;
        __syncthreads();
        sh[t] += u;
        __syncthreads();
    }
    if (t < NBUCK) bstart[t] = sh[t] - v;
    if (t == NBUCK - 1) bstart[NBUCK] = sh[t];
}

// ============ MERGED: blocks 0..NBB-1 = edge scatter; blocks NBB.. = persistent k1 ============
// k1: double-buffered x staging via global_load_lds; wpack in LDS; barrier drains vmcnt.
__global__ __launch_bounds__(256) void k_scat_k1(
    const int* __restrict__ ei,
    const int* __restrict__ boffB, const int* __restrict__ bstart,
    int* __restrict__ pairsP,
    const float* __restrict__ x,
    const float* __restrict__ w1a_b, const float* __restrict__ bp,
    const ushort_t* __restrict__ wpack,
    ushort_t* __restrict__ h1b, float* __restrict__ out1)
{
    __shared__ uint4 arena4[6144];      // 96 KB: wl(32K) | xbuf0(32K) | xbuf1(32K)
    const int t = threadIdx.x;

    if (blockIdx.x < NBB) {
        int* lcur = (int*)arena4;
        const int blk = blockIdx.x;
        for (int b = t; b < NBUCK; b += 256) lcur[b] = bstart[b] + boffB[b * NBB + blk];
        __syncthreads();
        const int base = blk * CHUNK;
        for (int i = t; i < CHUNK; i += 256) {
            const int src = ei[base + i];
            const int dst = ei[N_EDGES + base + i];
            const int b = dst / BUCK_W;
            const int pos = atomicAdd(&lcur[b], 1);
            pairsP[pos] = ((dst - b * BUCK_W) << 17) | src;
        }
        return;
    }

    // ---- persistent layer-1 MFMA ----
    bf16x8* wl = (bf16x8*)arena4;                 // 32 KB

    // stage wpack into LDS (covered by first loop barrier)
    {
        const uint4* src = (const uint4*)wpack;
        #pragma unroll
        for (int i = 0; i < 8; ++i) arena4[t + i * 256] = src[t + i * 256];
    }

    const int l64 = t & 63;
    const int wv  = t >> 6;
    const int pb  = (int)blockIdx.x - NBB;        // 0..K1P-1

    // stage helper: tile tt -> x buffer bufc (computed address, no pointer array)
    #define STAGE_X(bufc, tt)                                                     \
    {                                                                             \
        const int node0_ = (tt) * 32;                                             \
        char* xbase_ = (char*)arena4 + 32768 + (bufc) * 32768;                    \
        _Pragma("unroll")                                                         \
        for (int i_ = 0; i_ < 8; ++i_) {                                          \
            const int n_ = i_ * 4 + wv;                                           \
            int gn_ = node0_ + n_;                                                \
            if (gn_ >= N_NODES) gn_ = N_NODES - 1;                                \
            const char* gsrc_ = (const char*)x + (size_t)gn_ * 1024               \
                              + (size_t)((l64 ^ (n_ & 7)) * 16);                  \
            gload_lds16(gsrc_, xbase_ + (size_t)n_ * 1024);                       \
        }                                                                         \
    }

    const int q = wv >> 1;        // 0 -> h1b outputs, 1 -> out1 outputs
    const int s = wv & 1;         // subtile
    const int arow = l64 & 15;
    const int kq = l64 >> 4;
    const int nn = s * 16 + arow;
    const int sw = nn & 7;
    const int ch = l64 & 15;
    const int rbase = (l64 >> 4) * 4;
    const float b0 = q ? bp[ch]      : w1a_b[ch];
    const float b1 = q ? bp[ch + 16] : w1a_b[ch + 16];

    int ti = pb;
    int cur = 0;
    if (ti < NTILES) STAGE_X(0, ti)

    for (; ti < NTILES; ti += K1P) {
        __syncthreads();                          // drains cur buffer's async loads
        const int tn = ti + K1P;
        if (tn < NTILES) STAGE_X(cur ^ 1, tn)     // async prefetch next tile

        const char* xrow = (const char*)arena4 + 32768 + cur * 32768 + (size_t)nn * 1024;
        f32x4 acc0 = {0.f, 0.f, 0.f, 0.f};
        f32x4 acc1 = {0.f, 0.f, 0.f, 0.f};
        #pragma unroll
        for (int ks = 0; ks < 8; ++ks) {
            const int u0 = ks * 8 + kq * 2;
            const float4 xlo = *(const float4*)(xrow + ((u0 ^ sw) * 16));
            const float4 xhi = *(const float4*)(xrow + (((u0 + 1) ^ sw) * 16));
            const bf16x8 a = packA(xlo, xhi);
            const bf16x8 bf0 = wl[((q * 2) * 8 + ks) * 64 + l64];
            const bf16x8 bf1 = wl[((q * 2 + 1) * 8 + ks) * 64 + l64];
            acc0 = __builtin_amdgcn_mfma_f32_16x16x32_bf16(a, bf0, acc0, 0, 0, 0);
            acc1 = __builtin_amdgcn_mfma_f32_16x16x32_bf16(a, bf1, acc1, 0, 0, 0);
        }

        const int nodeb = ti * 32 + s * 16 + rbase;
        #pragma unroll
        for (int r = 0; r < 4; ++r) {
            const int node = nodeb + r;
            if (node < N_NODES) {
                if (q == 0) {
                    h1b[(size_t)node * HID + ch]      = f2bf(acc0[r] + b0);
                    h1b[(size_t)node * HID + ch + 16] = f2bf(acc1[r] + b1);
                } else {
                    out1[(size_t)node * HID + ch]      = acc0[r] + b0;
                    out1[(size_t)node * HID + ch + 16] = acc1[r] + b1;
                }
            }
        }
        cur ^= 1;
    }
    #undef STAGE_X
}

// ============ Aggregate layer 1: 512 thr, uint gather (2 ch/lane), persist sort ============
__global__ __launch_bounds__(512) void k_agg32(const int* __restrict__ bstart,
                                               const int* __restrict__ pairsP,
                                               const ushort_t* __restrict__ h1b,
                                               float* __restrict__ out1,
                                               int* __restrict__ colg,
                                               int* __restrict__ offg)
{
    __shared__ int cnt[128];
    __shared__ int off[129];
    __shared__ int srt[MAXE];
    const int t = threadIdx.x;
    const int b = blockIdx.x;
    const int c2 = t & 15;
    const int grp = t >> 4;
    const uint_t* h1u = (const uint_t*)h1b;

    const int e0g = bstart[b];
    const int e1g = bstart[b + 1];
    const bool single = (e1g - e0g) <= MAXE;

    for (int ch0 = e0g; ch0 < e1g; ch0 += MAXE) {
        const int ce = (ch0 + MAXE < e1g) ? (ch0 + MAXE) : e1g;
        const int cn = ce - ch0;

        if (t < 128) cnt[t] = 0;
        __syncthreads();
        for (int i = t; i < cn; i += 512)
            atomicAdd(&cnt[pairsP[ch0 + i] >> 17], 1);
        __syncthreads();
        {
            int v = (t < 128) ? cnt[t] : 0;
            if (t < 128) off[t] = v;
            __syncthreads();
            #pragma unroll
            for (int o = 1; o < 128; o <<= 1) {
                int u = 0;
                if (t < 128 && t >= o) u = off[t - o];
                __syncthreads();
                if (t < 128) off[t] += u;
                __syncthreads();
            }
            if (t < 128) {
                const int inc = off[t];
                off[t] = inc - v;
                cnt[t] = inc - v;
                if (t == 127) off[128] = inc;
            }
        }
        __syncthreads();
        for (int i = t; i < cn; i += 512) {
            const int p = pairsP[ch0 + i];
            const int pos = atomicAdd(&cnt[p >> 17], 1);
            srt[pos] = p & 0x1FFFF;
        }
        __syncthreads();
        if (single) {
            for (int i = t; i < cn; i += 512) colg[ch0 + i] = srt[i];
            if (t <= BUCK_W) offg[b * (BUCK_W + 1) + t] = e0g + off[t];
        }
        for (int n = grp; n < BUCK_W; n += 32) {
            const int e0 = off[n];
            const int e1 = off[n + 1];
            float l0 = 0.f, h0 = 0.f, l1 = 0.f, h1 = 0.f;
            int e = e0;
            for (; e + 4 <= e1; e += 4) {
                const uint_t u0 = h1u[(size_t)srt[e]     * 16 + c2];
                const uint_t u1 = h1u[(size_t)srt[e + 1] * 16 + c2];
                const uint_t u2 = h1u[(size_t)srt[e + 2] * 16 + c2];
                const uint_t u3 = h1u[(size_t)srt[e + 3] * 16 + c2];
                l0 += bf_lo(u0); h0 += bf_hi(u0);
                l1 += bf_lo(u1); h1 += bf_hi(u1);
                l0 += bf_lo(u2); h0 += bf_hi(u2);
                l1 += bf_lo(u3); h1 += bf_hi(u3);
            }
            for (; e < e1; ++e) {
                const uint_t u = h1u[(size_t)srt[e] * 16 + c2];
                l0 += bf_lo(u); h0 += bf_hi(u);
            }
            float2* o = (float2*)&out1[((size_t)b * BUCK_W + n) * HID + 2 * c2];
            const float2 cur = *o;
            float2 nv;
            nv.x = fmaxf(cur.x + l0 + l1, 0.f);
            nv.y = fmaxf(cur.y + h0 + h1, 0.f);
            *o = nv;
        }
        __syncthreads();
    }
}

// ============ Layer 2 dense ============
__global__ __launch_bounds__(256) void k3_layer2_dense(
    const float* __restrict__ out1,
    const float* __restrict__ w2a_w, const float* __restrict__ w2a_b,
    const float* __restrict__ w2b_w, const float* __restrict__ w2b_b,
    ushort_t* __restrict__ h2b, float* __restrict__ out2)
{
    __shared__ float rs[64][33];
    __shared__ float h2s[64][17];
    __shared__ float wa[16][33];
    __shared__ float wb[16][17];

    const int t = threadIdx.x;
    const int node0 = blockIdx.x * 64;
    const int nrem = N_NODES - node0;

    for (int i = t; i < 16 * 32; i += 256)
        wa[i >> 5][i & 31] = w2a_w[i];
    if (t < 16 * 16) wb[t >> 4][t & 15] = w2b_w[t];
    for (int i = t; i < 64 * 32; i += 256) {
        int r = i >> 5, c = i & 31;
        float v = 0.f;
        if (r < nrem) v = out1[(size_t)(node0 + r) * HID + c];
        rs[r][c] = fmaxf(v, 0.f);
    }
    __syncthreads();

    const int o = t & 15;
    const int g = t >> 4;

    const float ba = w2a_b[o];
    float acc[4] = {};
    for (int c = 0; c < 32; ++c) {
        const float w = wa[o][c];
        #pragma unroll
        for (int j = 0; j < 4; ++j) acc[j] += rs[g * 4 + j][c] * w;
    }
    #pragma unroll
    for (int j = 0; j < 4; ++j) {
        const int ln = g * 4 + j;
        const float v = acc[j] + ba;
        h2s[ln][o] = v;
        if (ln < nrem) h2b[(size_t)(node0 + ln) * OUTC + o] = f2bf(v);
    }
    __syncthreads();

    const float bbv = w2b_b[o];
    float f[4] = {};
    for (int c = 0; c < 16; ++c) {
        const float w = wb[o][c];
        #pragma unroll
        for (int j = 0; j < 4; ++j) f[j] += h2s[g * 4 + j][c] * w;
    }
    #pragma unroll
    for (int j = 0; j < 4; ++j) {
        const int ln = g * 4 + j;
        if (ln < nrem) out2[(size_t)(node0 + ln) * OUTC + o] = f[j] + bbv;
    }
}

// ============ Aggregate layer 2 + log_softmax (uint gather, width-8 softmax) ============
__global__ __launch_bounds__(512) void k_agg16_sm(const int* __restrict__ bstart,
                                                  const int* __restrict__ pairsP,
                                                  const int* __restrict__ colg,
                                                  const int* __restrict__ offg,
                                                  const ushort_t* __restrict__ h2b,
                                                  float* __restrict__ out2)
{
    const int t = threadIdx.x;
    const int b = blockIdx.x;
    const int e0g = bstart[b];
    const int e1g = bstart[b + 1];
    const uint_t* h2u = (const uint_t*)h2b;

    if (e1g - e0g <= MAXE) {
        const int c2 = t & 7;
        const int grp = t >> 3;
        const int ob = b * (BUCK_W + 1);
        for (int n = grp; n < BUCK_W; n += 64) {
            const int e0 = offg[ob + n];
            const int e1 = offg[ob + n + 1];
            float l0 = 0.f, h0 = 0.f, l1 = 0.f, h1v = 0.f;
            int e = e0;
            for (; e + 4 <= e1; e += 4) {
                const uint_t u0 = h2u[(size_t)colg[e]     * 8 + c2];
                const uint_t u1 = h2u[(size_t)colg[e + 1] * 8 + c2];
                const uint_t u2 = h2u[(size_t)colg[e + 2] * 8 + c2];
                const uint_t u3 = h2u[(size_t)colg[e + 3] * 8 + c2];
                l0 += bf_lo(u0); h0 += bf_hi(u0);
                l1 += bf_lo(u1); h1v += bf_hi(u1);
                l0 += bf_lo(u2); h0 += bf_hi(u2);
                l1 += bf_lo(u3); h1v += bf_hi(u3);
            }
            for (; e < e1; ++e) {
                const uint_t u = h2u[(size_t)colg[e] * 8 + c2];
                l0 += bf_lo(u); h0 += bf_hi(u);
            }

            float2* op = (float2*)&out2[((size_t)b * BUCK_W + n) * OUTC + 2 * c2];
            const float2 cur = *op;
            const float v0 = cur.x + l0 + l1;
            const float v1 = cur.y + h0 + h1v;

            float m = fmaxf(v0, v1);
            #pragma unroll
            for (int o = 4; o > 0; o >>= 1)
                m = fmaxf(m, __shfl_xor(m, o, 8));
            float s = expf(v0 - m) + expf(v1 - m);
            #pragma unroll
            for (int o = 4; o > 0; o >>= 1)
                s += __shfl_xor(s, o, 8);
            const float lse = m + logf(s);
            float2 nv; nv.x = v0 - lse; nv.y = v1 - lse;
            *op = nv;
        }
        return;
    }

    __shared__ int cnt[128];
    __shared__ int off[129];
    __shared__ int srt[MAXE];
    const int c = t & 15;
    const int grp = t >> 4;

    for (int ch0 = e0g; ch0 < e1g; ch0 += MAXE) {
        const int ce = (ch0 + MAXE < e1g) ? (ch0 + MAXE) : e1g;
        const int cn = ce - ch0;
        const bool last = (ce == e1g);

        if (t < 128) cnt[t] = 0;
        __syncthreads();
        for (int i = t; i < cn; i += 512)
            atomicAdd(&cnt[pairsP[ch0 + i] >> 17], 1);
        __syncthreads();
        {
            int v = (t < 128) ? cnt[t] : 0;
            if (t < 128) off[t] = v;
            __syncthreads();
            #pragma unroll
            for (int o = 1; o < 128; o <<= 1) {
                int u = 0;
                if (t < 128 && t >= o) u = off[t - o];
                __syncthreads();
                if (t < 128) off[t] += u;
                __syncthreads();
            }
            if (t < 128) {
                const int inc = off[t];
                off[t] = inc - v;
                cnt[t] = inc - v;
                if (t == 127) off[128] = inc;
            }
        }
        __syncthreads();
        for (int i = t; i < cn; i += 512) {
            const int p = pairsP[ch0 + i];
            const int pos = atomicAdd(&cnt[p >> 17], 1);
            srt[pos] = p & 0x1FFFF;
        }
        __syncthreads();

        for (int n = grp; n < BUCK_W; n += 32) {
            const int e0 = off[n];
            const int e1 = off[n + 1];
            float acc = 0.f, acc2 = 0.f;
            int e = e0;
            for (; e + 1 < e1; e += 2) {
                acc += bf2f(h2b[(size_t)srt[e] * OUTC + c]);
                acc2 += bf2f(h2b[(size_t)srt[e + 1] * OUTC + c]);
            }
            if (e < e1) acc += bf2f(h2b[(size_t)srt[e] * OUTC + c]);
            acc += acc2;

            const size_t oidx = ((size_t)b * BUCK_W + n) * OUTC + c;
            if (!last) {
                out2[oidx] += acc;
            } else {
                const float val = out2[oidx] + acc;
                float m = val;
                #pragma unroll
                for (int o = 8; o > 0; o >>= 1)
                    m = fmaxf(m, __shfl_xor(m, o, 16));
                float s = expf(val - m);
                #pragma unroll
                for (int o = 8; o > 0; o >>= 1)
                    s += __shfl_xor(s, o, 16);
                const float lse = m + logf(s);
                out2[oidx] = val - lse;
            }
        }
        __syncthreads();
    }
}

extern "C" void kernel_launch(void* const* d_in, const int* in_sizes, int n_in,
                              void* d_out, int out_size, void* d_ws, size_t ws_size,
                              hipStream_t stream)
{
    const float* x      = (const float*)d_in[0];
    const float* w1a_w  = (const float*)d_in[1];
    const float* w1a_b  = (const float*)d_in[2];
    const float* w1b_w  = (const float*)d_in[3];
    const float* w1b_b  = (const float*)d_in[4];
    const float* w2a_w  = (const float*)d_in[5];
    const float* w2a_b  = (const float*)d_in[6];
    const float* w2b_w  = (const float*)d_in[7];
    const float* w2b_b  = (const float*)d_in[8];
    const int*   ei     = (const int*)d_in[9];
    float* out = (float*)d_out;

    // workspace (~38 MB)
    float*    out1   = (float*)d_ws;                              // 12.8 MB
    ushort_t* h1b    = (ushort_t*)(out1 + (size_t)N_NODES * HID); // 6.4 MB
    ushort_t* h2b    = h1b + (size_t)N_NODES * HID;               // 3.2 MB
    int*      pairsP = (int*)(h2b + (size_t)N_NODES * OUTC);      // 6.4 MB
    ushort_t* wpack  = (ushort_t*)(pairsP + N_EDGES);             // 32 KB
    float*    bp     = (float*)(wpack + 4 * 8 * 64 * 8);          // 32 f32
    int*      bhist  = (int*)(bp + 32);                           // 1 MB
    int*      boffB  = bhist + NBUCK * NBB;                       // 1 MB
    int*      btot   = boffB + NBUCK * NBB;                       // 1000
    int*      bstart = btot + NBUCK;                              // 1001
    int*      colg   = bstart + NBUCK + 1;                        // 6.4 MB
    int*      offg   = colg + N_EDGES;                            // ~404 KB

    k_cnt_wfuse<<<NBB + 1, 256, 0, stream>>>(ei, bhist,
                                             w1a_w, w1a_b, w1b_w, w1b_b, wpack, bp);
    k_scanH <<<NBUCK, 256, 0, stream>>>(bhist, boffB, btot);
    k_scanH2<<<1, 1024, 0, stream>>>(btot, bstart);
    k_scat_k1<<<NBB + K1P, 256, 0, stream>>>(ei, boffB, bstart, pairsP,
                                             x, w1a_b, bp, wpack, h1b, out1);
    k_agg32<<<NBUCK, 512, 0, stream>>>(bstart, pairsP, h1b, out1, colg, offg);
    k3_layer2_dense<<<(N_NODES + 63) / 64, 256, 0, stream>>>(out1, w2a_w, w2a_b, w2b_w, w2b_b, h2b, out);
    k_agg16_sm<<<NBUCK, 512, 0, stream>>>(bstart, pairsP, colg, offg, h2b, out);
}

// Round 26
// 126.226 us; speedup vs baseline: 1.1167x; 1.1155x over previous
//
#include <hip/hip_runtime.h>
#include <hip/hip_bf16.h>
#include <math.h>

#define N_NODES 100000
#define N_EDGES 1600000
#define IN_F 256
#define HID 32
#define OUTC 16
#define NBUCK 1000
#define BUCK_W 100     // NBUCK * BUCK_W == N_NODES
#define NBB 256        // partition blocks
#define CHUNK 6250     // N_EDGES / NBB
#define MAXE 3072      // per-chunk edge capacity in LDS (max real bucket ~1732)
#define K1_BLOCKS ((N_NODES + 63) / 64)   // 1563

typedef unsigned short ushort_t;
typedef unsigned int uint_t;
typedef __attribute__((ext_vector_type(8))) short bf16x8;
typedef __attribute__((ext_vector_type(4))) float f32x4;

__device__ inline ushort_t f2bf(float f) {
    union { float f; uint_t u; } v; v.f = f;
    uint_t r = v.u + 0x7fff + ((v.u >> 16) & 1);
    return (ushort_t)(r >> 16);
}
__device__ inline float bf2f(ushort_t h) {
    union { uint_t u; float f; } v; v.u = (uint_t)h << 16;
    return v.f;
}
__device__ inline float bf_lo(uint_t d) {
    union { uint_t u; float f; } v; v.u = d << 16;
    return v.f;
}
__device__ inline float bf_hi(uint_t d) {
    union { uint_t u; float f; } v; v.u = d & 0xFFFF0000u;
    return v.f;
}
__device__ inline bf16x8 packA(const float4& lo, const float4& hi) {
    bf16x8 a;
    a[0] = (short)f2bf(lo.x); a[1] = (short)f2bf(lo.y);
    a[2] = (short)f2bf(lo.z); a[3] = (short)f2bf(lo.w);
    a[4] = (short)f2bf(hi.x); a[5] = (short)f2bf(hi.y);
    a[6] = (short)f2bf(hi.z); a[7] = (short)f2bf(hi.w);
    return a;
}

// ============ MERGED: blocks 0..NBB-1 = bucket histogram; block NBB = weight fusion ============
__global__ __launch_bounds__(256) void k_cnt_wfuse(
    const int* __restrict__ ei, int* __restrict__ bhist,
    const float* __restrict__ w1a_w, const float* __restrict__ w1a_b,
    const float* __restrict__ w1b_w, const float* __restrict__ w1b_b,
    ushort_t* __restrict__ wpack, float* __restrict__ bp)
{
    __shared__ char smem[32 * 1024 + 4 * 1024 + 256];
    const int t = threadIdx.x;

    if (blockIdx.x < NBB) {
        int* lh = (int*)smem;
        const int blk = blockIdx.x;
        for (int b = t; b < NBUCK; b += 256) lh[b] = 0;
        __syncthreads();
        const int base = blk * CHUNK;
        for (int i = t; i < CHUNK; i += 256) {
            const int dst = ei[N_EDGES + base + i];
            atomicAdd(&lh[dst / BUCK_W], 1);
        }
        __syncthreads();
        for (int b = t; b < NBUCK; b += 256) bhist[b * NBB + blk] = lh[b];
        return;
    }

    float (*wps)[256] = (float (*)[256])smem;
    float (*wb_s)[32] = (float (*)[32])(smem + 32 * 1024);
    float* ba_s       = (float*)(smem + 36 * 1024);
    for (int i = t; i < 1024; i += 256) wb_s[i >> 5][i & 31] = w1b_w[i];
    if (t < 32) ba_s[t] = w1a_b[t];
    __syncthreads();
    const int k = t;
    for (int o = 0; o < 32; ++o) {
        float s = 0.f;
        #pragma unroll 8
        for (int c = 0; c < 32; ++c) s += wb_s[o][c] * w1a_w[c * 256 + k];
        wps[o][k] = s;
    }
    if (t < 32) {
        float s = 0.f;
        for (int c = 0; c < 32; ++c) s += wb_s[t][c] * ba_s[c];
        bp[t] = s + w1b_b[t];
    }
    __syncthreads();
    for (int idx = t; idx < 4 * 8 * 64 * 8; idx += 256) {
        const int j  = idx & 7;
        const int l  = (idx >> 3) & 63;
        const int ks = (idx >> 9) & 7;
        const int q  = idx >> 12;
        const int ncol = ((q & 1) << 4) + (l & 15);
        const int krow = ks * 32 + ((l >> 4) << 3) + j;
        const float v = (q < 2) ? w1a_w[ncol * 256 + krow] : wps[ncol][krow];
        wpack[idx] = f2bf(v);
    }
}

// ============ Pass 2a ============
__global__ __launch_bounds__(256) void k_scanH(const int* __restrict__ bhist,
                                               int* __restrict__ boffB, int* __restrict__ btot)
{
    __shared__ int sh[256];
    const int t = threadIdx.x;
    const int b = blockIdx.x;
    const int v = bhist[b * NBB + t];
    sh[t] = v;
    __syncthreads();
    #pragma unroll
    for (int off = 1; off < 256; off <<= 1) {
        const int u = (t >= off) ? sh[t - off] : 0;
        __syncthreads();
        sh[t] += u;
        __syncthreads();
    }
    boffB[b * NBB + t] = sh[t] - v;
    if (t == 255) btot[b] = sh[255];
}

// ============ Pass 2b ============
__global__ __launch_bounds__(1024) void k_scanH2(const int* __restrict__ btot,
                                                 int* __restrict__ bstart)
{
    __shared__ int sh[1024];
    const int t = threadIdx.x;
    const int v = (t < NBUCK) ? btot[t] : 0;
    sh[t] = v;
    __syncthreads();
    #pragma unroll
    for (int off = 1; off < 1024; off <<= 1) {
        const int u = (t >= off) ? sh[t - off] : 0;
        __syncthreads();
        sh[t] += u;
        __syncthreads();
    }
    if (t < NBUCK) bstart[t] = sh[t] - v;
    if (t == NBUCK - 1) bstart[NBUCK] = sh[t];
}

// ============ MERGED: blocks 0..NBB-1 = edge scatter; blocks NBB.. = layer-1 MFMA ============
// k1: B-fragments staged in LDS (32 KB) -> only 2 global loads per ks iteration.
__global__ __launch_bounds__(256) void k_scat_k1(
    const int* __restrict__ ei,
    const int* __restrict__ boffB, const int* __restrict__ bstart,
    int* __restrict__ pairsP,
    const float* __restrict__ x,
    const float* __restrict__ w1a_b, const float* __restrict__ bp,
    const ushort_t* __restrict__ wpack,
    ushort_t* __restrict__ h1b, float* __restrict__ out1)
{
    __shared__ char arena[32 * 1024];   // scat: lcur (4KB) | k1: wfrag (32KB)
    const int t = threadIdx.x;

    if (blockIdx.x < NBB) {
        int* lcur = (int*)arena;
        const int blk = blockIdx.x;
        for (int b = t; b < NBUCK; b += 256) lcur[b] = bstart[b] + boffB[b * NBB + blk];
        __syncthreads();
        const int base = blk * CHUNK;
        for (int i = t; i < CHUNK; i += 256) {
            const int src = ei[base + i];
            const int dst = ei[N_EDGES + base + i];
            const int b = dst / BUCK_W;
            const int pos = atomicAdd(&lcur[b], 1);
            pairsP[pos] = ((dst - b * BUCK_W) << 17) | src;
        }
        return;
    }

    // stage all B-fragments into LDS (32 KB, coalesced)
    bf16x8* wl = (bf16x8*)arena;
    {
        const uint4* src = (const uint4*)wpack;
        uint4* dst = (uint4*)arena;
        #pragma unroll
        for (int i = 0; i < 8; ++i) dst[t + i * 256] = src[t + i * 256];
    }
    __syncthreads();

    const int lane = t & 63;
    const int wv = t >> 6;
    const int node0 = (int)(blockIdx.x - NBB) * 64 + wv * 16;

    const int arow = lane & 15;
    const int kq   = lane >> 4;
    int nodeA = node0 + arow;
    if (nodeA >= N_NODES) nodeA = N_NODES - 1;

    const float* xr = x + (size_t)nodeA * IN_F + kq * 8;

    f32x4 accA0 = {0.f, 0.f, 0.f, 0.f};
    f32x4 accA1 = {0.f, 0.f, 0.f, 0.f};
    f32x4 accB0 = {0.f, 0.f, 0.f, 0.f};
    f32x4 accB1 = {0.f, 0.f, 0.f, 0.f};

    #pragma unroll
    for (int ks = 0; ks < 8; ++ks) {
        const float4 xlo = *(const float4*)(xr + ks * 32);
        const float4 xhi = *(const float4*)(xr + ks * 32 + 4);
        const bf16x8 a = packA(xlo, xhi);
        const bf16x8 bA0 = wl[(0 * 8 + ks) * 64 + lane];
        const bf16x8 bA1 = wl[(1 * 8 + ks) * 64 + lane];
        const bf16x8 bB0 = wl[(2 * 8 + ks) * 64 + lane];
        const bf16x8 bB1 = wl[(3 * 8 + ks) * 64 + lane];
        accA0 = __builtin_amdgcn_mfma_f32_16x16x32_bf16(a, bA0, accA0, 0, 0, 0);
        accA1 = __builtin_amdgcn_mfma_f32_16x16x32_bf16(a, bA1, accA1, 0, 0, 0);
        accB0 = __builtin_amdgcn_mfma_f32_16x16x32_bf16(a, bB0, accB0, 0, 0, 0);
        accB1 = __builtin_amdgcn_mfma_f32_16x16x32_bf16(a, bB1, accB1, 0, 0, 0);
    }

    const int ch = lane & 15;
    const int rbase = (lane >> 4) * 4;
    const float ba0 = w1a_b[ch];
    const float ba1 = w1a_b[ch + 16];
    const float bb0 = bp[ch];
    const float bb1 = bp[ch + 16];

    #pragma unroll
    for (int r = 0; r < 4; ++r) {
        const int node = node0 + rbase + r;
        if (node < N_NODES) {
            h1b[(size_t)node * HID + ch]       = f2bf(accA0[r] + ba0);
            h1b[(size_t)node * HID + ch + 16]  = f2bf(accA1[r] + ba1);
            out1[(size_t)node * HID + ch]      = accB0[r] + bb0;
            out1[(size_t)node * HID + ch + 16] = accB1[r] + bb1;
        }
    }
}

// ============ FUSED: aggregate layer 1 + layer 2 dense (occupancy-preserving) ============
// LDS 35.7 KB -> 4 blocks/CU (thread-capped, same as split agg32).
// rsf = out1_dense; gather += rsf; relu; h2 = rsf@W2a^T+b -> h2b; out = h2@W2b^T+b.
__global__ __launch_bounds__(512) void k_agg32_l2(
    const int* __restrict__ bstart, const int* __restrict__ pairsP,
    const ushort_t* __restrict__ h1b, const float* __restrict__ out1,
    const float* __restrict__ w2a_w, const float* __restrict__ w2a_b,
    const float* __restrict__ w2b_w, const float* __restrict__ w2b_b,
    ushort_t* __restrict__ h2b, float* __restrict__ out2,
    int* __restrict__ colg, int* __restrict__ offg)
{
    __shared__ int   cnt[128];
    __shared__ int   off[129];
    __shared__ int   srt[MAXE];            // 12 KB
    __shared__ float rsf[BUCK_W * 33];     // 13.2 KB
    __shared__ float h2s[BUCK_W * 17];     // 6.8 KB
    __shared__ float wa[16][33];           // 2.1 KB
    __shared__ float wb[16][17];           // 1.1 KB

    const int t = threadIdx.x;
    const int b = blockIdx.x;
    const int c2 = t & 15;
    const int grp = t >> 4;                // 32 groups of 16 lanes
    const int nbase = b * BUCK_W;
    const uint_t* h1u = (const uint_t*)h1b;

    // weights + rsf init from dense out1
    if (t < 512) wa[t >> 5][t & 31] = w2a_w[t];
    if (t < 256) wb[t >> 4][t & 15] = w2b_w[t];
    for (int i = t; i < BUCK_W * HID; i += 512)
        rsf[(i >> 5) * 33 + (i & 31)] = out1[(size_t)nbase * HID + i];
    __syncthreads();

    const int e0g = bstart[b];
    const int e1g = bstart[b + 1];
    const bool single = (e1g - e0g) <= MAXE;

    for (int ch0 = e0g; ch0 < e1g; ch0 += MAXE) {
        const int ce = (ch0 + MAXE < e1g) ? (ch0 + MAXE) : e1g;
        const int cn = ce - ch0;

        if (t < 128) cnt[t] = 0;
        __syncthreads();
        for (int i = t; i < cn; i += 512)
            atomicAdd(&cnt[pairsP[ch0 + i] >> 17], 1);
        __syncthreads();
        {
            int v = (t < 128) ? cnt[t] : 0;
            if (t < 128) off[t] = v;
            __syncthreads();
            #pragma unroll
            for (int o = 1; o < 128; o <<= 1) {
                int u = 0;
                if (t < 128 && t >= o) u = off[t - o];
                __syncthreads();
                if (t < 128) off[t] += u;
                __syncthreads();
            }
            if (t < 128) {
                const int inc = off[t];
                off[t] = inc - v;
                cnt[t] = inc - v;
                if (t == 127) off[128] = inc;
            }
        }
        __syncthreads();
        for (int i = t; i < cn; i += 512) {
            const int p = pairsP[ch0 + i];
            const int pos = atomicAdd(&cnt[p >> 17], 1);
            srt[pos] = p & 0x1FFFF;
        }
        __syncthreads();
        if (single) {
            for (int i = t; i < cn; i += 512) colg[ch0 + i] = srt[i];
            if (t <= BUCK_W) offg[b * (BUCK_W + 1) + t] = e0g + off[t];
        }
        // gather: 4-deep unrolled uint loads; accumulate into rsf (unique owner per (n,c2))
        for (int n = grp; n < BUCK_W; n += 32) {
            const int e0 = off[n];
            const int e1 = off[n + 1];
            float l0 = 0.f, h0 = 0.f, l1 = 0.f, h1 = 0.f;
            int e = e0;
            for (; e + 4 <= e1; e += 4) {
                const uint_t u0 = h1u[(size_t)srt[e]     * 16 + c2];
                const uint_t u1 = h1u[(size_t)srt[e + 1] * 16 + c2];
                const uint_t u2 = h1u[(size_t)srt[e + 2] * 16 + c2];
                const uint_t u3 = h1u[(size_t)srt[e + 3] * 16 + c2];
                l0 += bf_lo(u0); h0 += bf_hi(u0);
                l1 += bf_lo(u1); h1 += bf_hi(u1);
                l0 += bf_lo(u2); h0 += bf_hi(u2);
                l1 += bf_lo(u3); h1 += bf_hi(u3);
            }
            for (; e < e1; ++e) {
                const uint_t u = h1u[(size_t)srt[e] * 16 + c2];
                l0 += bf_lo(u); h0 += bf_hi(u);
            }
            rsf[n * 33 + 2 * c2]     += l0 + l1;
            rsf[n * 33 + 2 * c2 + 1] += h0 + h1;
        }
        __syncthreads();
    }

    // relu once
    for (int i = t; i < BUCK_W * HID; i += 512) {
        const int idx = (i >> 5) * 33 + (i & 31);
        rsf[idx] = fmaxf(rsf[idx], 0.f);
    }
    __syncthreads();

    // layer-2 dense: h2 = rsf@W2a^T + b2a
    {
        const int o = t & 15;
        const int ng = t >> 4;
        const float ba = w2a_b[o];
        for (int n = ng; n < BUCK_W; n += 32) {
            float acc = 0.f;
            #pragma unroll 8
            for (int cc = 0; cc < 32; ++cc)
                acc += rsf[n * 33 + cc] * wa[o][cc];
            const float v = acc + ba;
            h2s[n * 17 + o] = v;
            h2b[(size_t)(nbase + n) * OUTC + o] = f2bf(v);
        }
    }
    __syncthreads();

    // out_dense = h2@W2b^T + b2b
    {
        const int o = t & 15;
        const int ng = t >> 4;
        const float bbv = w2b_b[o];
        for (int n = ng; n < BUCK_W; n += 32) {
            float f = 0.f;
            #pragma unroll 8
            for (int cc = 0; cc < 16; ++cc)
                f += h2s[n * 17 + cc] * wb[o][cc];
            out2[(size_t)(nbase + n) * OUTC + o] = f + bbv;
        }
    }
}

// ============ Aggregate layer 2 + log_softmax (uint gather, width-8 softmax) ============
__global__ __launch_bounds__(512) void k_agg16_sm(const int* __restrict__ bstart,
                                                  const int* __restrict__ pairsP,
                                                  const int* __restrict__ colg,
                                                  const int* __restrict__ offg,
                                                  const ushort_t* __restrict__ h2b,
                                                  float* __restrict__ out2)
{
    const int t = threadIdx.x;
    const int b = blockIdx.x;
    const int e0g = bstart[b];
    const int e1g = bstart[b + 1];
    const uint_t* h2u = (const uint_t*)h2b;

    if (e1g - e0g <= MAXE) {
        const int c2 = t & 7;
        const int grp = t >> 3;
        const int ob = b * (BUCK_W + 1);
        for (int n = grp; n < BUCK_W; n += 64) {
            const int e0 = offg[ob + n];
            const int e1 = offg[ob + n + 1];
            float l0 = 0.f, h0 = 0.f, l1 = 0.f, h1v = 0.f;
            int e = e0;
            for (; e + 4 <= e1; e += 4) {
                const uint_t u0 = h2u[(size_t)colg[e]     * 8 + c2];
                const uint_t u1 = h2u[(size_t)colg[e + 1] * 8 + c2];
                const uint_t u2 = h2u[(size_t)colg[e + 2] * 8 + c2];
                const uint_t u3 = h2u[(size_t)colg[e + 3] * 8 + c2];
                l0 += bf_lo(u0); h0 += bf_hi(u0);
                l1 += bf_lo(u1); h1v += bf_hi(u1);
                l0 += bf_lo(u2); h0 += bf_hi(u2);
                l1 += bf_lo(u3); h1v += bf_hi(u3);
            }
            for (; e < e1; ++e) {
                const uint_t u = h2u[(size_t)colg[e] * 8 + c2];
                l0 += bf_lo(u); h0 += bf_hi(u);
            }

            float2* op = (float2*)&out2[((size_t)b * BUCK_W + n) * OUTC + 2 * c2];
            const float2 cur = *op;
            const float v0 = cur.x + l0 + l1;
            const float v1 = cur.y + h0 + h1v;

            float m = fmaxf(v0, v1);
            #pragma unroll
            for (int o = 4; o > 0; o >>= 1)
                m = fmaxf(m, __shfl_xor(m, o, 8));
            float s = expf(v0 - m) + expf(v1 - m);
            #pragma unroll
            for (int o = 4; o > 0; o >>= 1)
                s += __shfl_xor(s, o, 8);
            const float lse = m + logf(s);
            float2 nv; nv.x = v0 - lse; nv.y = v1 - lse;
            *op = nv;
        }
        return;
    }

    __shared__ int cnt[128];
    __shared__ int off[129];
    __shared__ int srt[MAXE];
    const int c = t & 15;
    const int grp = t >> 4;

    for (int ch0 = e0g; ch0 < e1g; ch0 += MAXE) {
        const int ce = (ch0 + MAXE < e1g) ? (ch0 + MAXE) : e1g;
        const int cn = ce - ch0;
        const bool last = (ce == e1g);

        if (t < 128) cnt[t] = 0;
        __syncthreads();
        for (int i = t; i < cn; i += 512)
            atomicAdd(&cnt[pairsP[ch0 + i] >> 17], 1);
        __syncthreads();
        {
            int v = (t < 128) ? cnt[t] : 0;
            if (t < 128) off[t] = v;
            __syncthreads();
            #pragma unroll
            for (int o = 1; o < 128; o <<= 1) {
                int u = 0;
                if (t < 128 && t >= o) u = off[t - o];
                __syncthreads();
                if (t < 128) off[t] += u;
                __syncthreads();
            }
            if (t < 128) {
                const int inc = off[t];
                off[t] = inc - v;
                cnt[t] = inc - v;
                if (t == 127) off[128] = inc;
            }
        }
        __syncthreads();
        for (int i = t; i < cn; i += 512) {
            const int p = pairsP[ch0 + i];
            const int pos = atomicAdd(&cnt[p >> 17], 1);
            srt[pos] = p & 0x1FFFF;
        }
        __syncthreads();

        for (int n = grp; n < BUCK_W; n += 32) {
            const int e0 = off[n];
            const int e1 = off[n + 1];
            float acc = 0.f, acc2 = 0.f;
            int e = e0;
            for (; e + 1 < e1; e += 2) {
                acc += bf2f(h2b[(size_t)srt[e] * OUTC + c]);
                acc2 += bf2f(h2b[(size_t)srt[e + 1] * OUTC + c]);
            }
            if (e < e1) acc += bf2f(h2b[(size_t)srt[e] * OUTC + c]);
            acc += acc2;

            const size_t oidx = ((size_t)b * BUCK_W + n) * OUTC + c;
            if (!last) {
                out2[oidx] += acc;
            } else {
                const float val = out2[oidx] + acc;
                float m = val;
                #pragma unroll
                for (int o = 8; o > 0; o >>= 1)
                    m = fmaxf(m, __shfl_xor(m, o, 16));
                float s = expf(val - m);
                #pragma unroll
                for (int o = 8; o > 0; o >>= 1)
                    s += __shfl_xor(s, o, 16);
                const float lse = m + logf(s);
                out2[oidx] = val - lse;
            }
        }
        __syncthreads();
    }
}

extern "C" void kernel_launch(void* const* d_in, const int* in_sizes, int n_in,
                              void* d_out, int out_size, void* d_ws, size_t ws_size,
                              hipStream_t stream)
{
    const float* x      = (const float*)d_in[0];
    const float* w1a_w  = (const float*)d_in[1];
    const float* w1a_b  = (const float*)d_in[2];
    const float* w1b_w  = (const float*)d_in[3];
    const float* w1b_b  = (const float*)d_in[4];
    const float* w2a_w  = (const float*)d_in[5];
    const float* w2a_b  = (const float*)d_in[6];
    const float* w2b_w  = (const float*)d_in[7];
    const float* w2b_b  = (const float*)d_in[8];
    const int*   ei     = (const int*)d_in[9];
    float* out = (float*)d_out;

    // workspace (~38 MB)
    float*    out1   = (float*)d_ws;                              // 12.8 MB
    ushort_t* h1b    = (ushort_t*)(out1 + (size_t)N_NODES * HID); // 6.4 MB
    ushort_t* h2b    = h1b + (size_t)N_NODES * HID;               // 3.2 MB
    int*      pairsP = (int*)(h2b + (size_t)N_NODES * OUTC);      // 6.4 MB
    ushort_t* wpack  = (ushort_t*)(pairsP + N_EDGES);             // 32 KB
    float*    bp     = (float*)(wpack + 4 * 8 * 64 * 8);          // 32 f32
    int*      bhist  = (int*)(bp + 32);                           // 1 MB
    int*      boffB  = bhist + NBUCK * NBB;                       // 1 MB
    int*      btot   = boffB + NBUCK * NBB;                       // 1000
    int*      bstart = btot + NBUCK;                              // 1001
    int*      colg   = bstart + NBUCK + 1;                        // 6.4 MB
    int*      offg   = colg + N_EDGES;                            // ~404 KB

    k_cnt_wfuse<<<NBB + 1, 256, 0, stream>>>(ei, bhist,
                                             w1a_w, w1a_b, w1b_w, w1b_b, wpack, bp);
    k_scanH <<<NBUCK, 256, 0, stream>>>(bhist, boffB, btot);
    k_scanH2<<<1, 1024, 0, stream>>>(btot, bstart);
    k_scat_k1<<<NBB + K1_BLOCKS, 256, 0, stream>>>(ei, boffB, bstart, pairsP,
                                                   x, w1a_b, bp, wpack, h1b, out1);
    k_agg32_l2<<<NBUCK, 512, 0, stream>>>(bstart, pairsP, h1b, out1,
                                          w2a_w, w2a_b, w2b_w, w2b_b,
                                          h2b, out, colg, offg);
    k_agg16_sm<<<NBUCK, 512, 0, stream>>>(bstart, pairsP, colg, offg, h2b, out);
}